// Round 1
// baseline (419.271 us; speedup 1.0000x reference)
//
#include <hip/hip_runtime.h>
#include <hip/hip_bf16.h>

// Problem constants: B=4, S=1024, D=1024, H=16, HD=64
#define SS 1024
#define DD 1024
#define HH 16
#define HDh 64

typedef short bf16x8 __attribute__((ext_vector_type(8)));
typedef float f32x4 __attribute__((ext_vector_type(4)));

__device__ inline unsigned short f2bf(float f) {
    union { __hip_bfloat16 h; unsigned short u; } cv;
    cv.h = __float2bfloat16(f);   // RTNE
    return cv.u;
}

// ---------------- fp32 -> bf16 convert for query/key/value ----------------
__global__ __launch_bounds__(256) void cvt3(
    const float* __restrict__ a, const float* __restrict__ b, const float* __restrict__ c,
    unsigned short* __restrict__ oa, unsigned short* __restrict__ ob, unsigned short* __restrict__ oc)
{
    size_t i = ((size_t)blockIdx.x * 256 + threadIdx.x) * 4;
    float4 va = *(const float4*)(a + i);
    float4 vb = *(const float4*)(b + i);
    float4 vc = *(const float4*)(c + i);
    *(ushort4*)(oa + i) = make_ushort4(f2bf(va.x), f2bf(va.y), f2bf(va.z), f2bf(va.w));
    *(ushort4*)(ob + i) = make_ushort4(f2bf(vb.x), f2bf(vb.y), f2bf(vb.z), f2bf(vb.w));
    *(ushort4*)(oc + i) = make_ushort4(f2bf(vc.x), f2bf(vc.y), f2bf(vc.z), f2bf(vc.w));
}

// ------------- weight transpose-convert: Wt[e][d] = bf16(W[d][e]) -------------
// B-operand of mfma wants [n][k] contiguous in k; W is [d(k)][e(n)] row-major.
__global__ __launch_bounds__(256) void wtrans(
    const float* __restrict__ Wq, const float* __restrict__ Wk,
    const float* __restrict__ Wv, const float* __restrict__ Wo,
    unsigned short* __restrict__ oq, unsigned short* __restrict__ ok,
    unsigned short* __restrict__ ov, unsigned short* __restrict__ oo)
{
    __shared__ float tile[32][33];
    int z = blockIdx.z;
    const float* W = z == 0 ? Wq : (z == 1 ? Wk : (z == 2 ? Wv : Wo));
    unsigned short* O = z == 0 ? oq : (z == 1 ? ok : (z == 2 ? ov : oo));
    int e0 = blockIdx.x * 32, d0 = blockIdx.y * 32;
    int r = threadIdx.x >> 3, c4 = (threadIdx.x & 7) * 4;
    float4 v = *(const float4*)(W + (size_t)(d0 + r) * DD + e0 + c4);
    tile[r][c4 + 0] = v.x; tile[r][c4 + 1] = v.y; tile[r][c4 + 2] = v.z; tile[r][c4 + 3] = v.w;
    __syncthreads();
    // out element (e0+r, d0+c4+i) = W[d0+c4+i][e0+r] = tile[c4+i][r]
    ushort4 u = make_ushort4(f2bf(tile[c4 + 0][r]), f2bf(tile[c4 + 1][r]),
                             f2bf(tile[c4 + 2][r]), f2bf(tile[c4 + 3][r]));
    *(ushort4*)(O + (size_t)(e0 + r) * DD + d0 + c4) = u;
}

// ---------------- 128x128 bf16 MFMA GEMM core ----------------
// C[m][n] = sum_k A[m][k]*Bt[n][k] + bias[n]
// 256 threads = 4 waves in 2x2; each wave 64x64 = 4x4 frags of 16x16x32.
// mode 0: bf16 out at [b,h,s,hd]; mode 1: bf16 out at [b,h,hd,s] (V^T); mode 2: f32 row-major.
__device__ inline void gemm128_core(const unsigned short* __restrict__ A,
                                    const unsigned short* __restrict__ Bt,
                                    const float* __restrict__ bias,
                                    void* __restrict__ out, int mode)
{
    __shared__ unsigned short As[128][48];   // stride 48 ushort = 96B (16B-aligned rows)
    __shared__ unsigned short Bs[128][48];
    int t = threadIdx.x;
    int m0 = blockIdx.y * 128, n0 = blockIdx.x * 128;
    int w = t >> 6, lane = t & 63, quad = lane >> 4, l15 = lane & 15;
    int wm = w >> 1, wn = w & 1;

    f32x4 zero = {0.f, 0.f, 0.f, 0.f};
    f32x4 acc[4][4];
#pragma unroll
    for (int i = 0; i < 4; i++)
#pragma unroll
        for (int j = 0; j < 4; j++) acc[i][j] = zero;

    for (int k0 = 0; k0 < DD; k0 += 32) {
        __syncthreads();
#pragma unroll
        for (int i = 0; i < 2; i++) {
            int u = t * 2 + i;              // 0..511 b128 units
            int row = u >> 2, kc = (u & 3) * 8;
            *(uint4*)&As[row][kc] = *(const uint4*)(A + (size_t)(m0 + row) * DD + k0 + kc);
            *(uint4*)&Bs[row][kc] = *(const uint4*)(Bt + (size_t)(n0 + row) * DD + k0 + kc);
        }
        __syncthreads();
        bf16x8 af[4], bfr[4];
#pragma unroll
        for (int mi = 0; mi < 4; mi++)
            af[mi] = *(const bf16x8*)&As[wm * 64 + mi * 16 + l15][quad * 8];
#pragma unroll
        for (int ni = 0; ni < 4; ni++)
            bfr[ni] = *(const bf16x8*)&Bs[wn * 64 + ni * 16 + l15][quad * 8];
#pragma unroll
        for (int mi = 0; mi < 4; mi++)
#pragma unroll
            for (int ni = 0; ni < 4; ni++)
                acc[mi][ni] = __builtin_amdgcn_mfma_f32_16x16x32_bf16(af[mi], bfr[ni], acc[mi][ni], 0, 0, 0);
    }

    // epilogue: C/D layout col=lane&15, row=quad*4+reg
#pragma unroll
    for (int mi = 0; mi < 4; mi++)
#pragma unroll
        for (int ni = 0; ni < 4; ni++) {
            int n = n0 + wn * 64 + ni * 16 + l15;
            float bv = bias[n];
#pragma unroll
            for (int r = 0; r < 4; r++) {
                int m = m0 + wm * 64 + mi * 16 + quad * 4 + r;
                float v = acc[mi][ni][r] + bv;
                if (mode == 2) {
                    ((float*)out)[(size_t)m * DD + n] = v;
                } else {
                    int bb = m >> 10, s = m & 1023, hh = n >> 6, d = n & 63;
                    size_t off = (mode == 0)
                        ? (((size_t)(bb * HH + hh) * SS + s) * HDh + d)    // [b,h,s,hd]
                        : (((size_t)(bb * HH + hh) * HDh + d) * SS + s);   // [b,h,hd,s]
                    ((unsigned short*)out)[off] = f2bf(v);
                }
            }
        }
}

__global__ __launch_bounds__(256) void gemm_qkv(
    const unsigned short* __restrict__ xq, const unsigned short* __restrict__ xk,
    const unsigned short* __restrict__ xv,
    const unsigned short* __restrict__ wtq, const unsigned short* __restrict__ wtk,
    const unsigned short* __restrict__ wtv,
    const float* __restrict__ bq, const float* __restrict__ bk, const float* __restrict__ bv,
    unsigned short* __restrict__ q, unsigned short* __restrict__ k, unsigned short* __restrict__ v)
{
    int z = blockIdx.z;
    const unsigned short* A  = z == 0 ? xq  : (z == 1 ? xk  : xv);
    const unsigned short* Bt = z == 0 ? wtq : (z == 1 ? wtk : wtv);
    const float* bias        = z == 0 ? bq  : (z == 1 ? bk  : bv);
    void* out                = z == 0 ? (void*)q : (z == 1 ? (void*)k : (void*)v);
    gemm128_core(A, Bt, bias, out, z == 2 ? 1 : 0);
}

__global__ __launch_bounds__(256) void gemm_o(
    const unsigned short* __restrict__ x, const unsigned short* __restrict__ wto,
    const float* __restrict__ bo, float* __restrict__ out)
{
    gemm128_core(x, wto, bo, out, 2);
}

// ---------------- fused attention ----------------
// 256 blocks (b, q-tile of 16), 512 threads = 8 waves.
// S1 (QK^T/8) held in VGPRs in C-layout; full-row softmax (needed for attn_c anyway);
// P -> LDS (C-layout write, A-layout b128 read) -> P.V via MFMA with V^T from global.
__global__ __launch_bounds__(512) void attn_kernel(
    const unsigned short* __restrict__ qb, const unsigned short* __restrict__ kb,
    const unsigned short* __restrict__ vt, const float* __restrict__ Wc,
    const float* __restrict__ bcp, unsigned short* __restrict__ xout,
    float* __restrict__ attc)
{
    __shared__ float accc[16][1028];          // attn_c accumulator (pad 1028 -> 2-way max)
    __shared__ unsigned short Ps[16][1040];   // P in bf16 (stride 1040 ushort = 2080B, 16B-aligned)
    __shared__ float red[8][16];              // cross-wave softmax partials
    __shared__ float Ob[2][16][64];           // split-K P.V partials

    int t = threadIdx.x, w = t >> 6, lane = t & 63, quad = lane >> 4, l15 = lane & 15;
    int b = blockIdx.x >> 6, q0 = (blockIdx.x & 63) << 4;

    for (int i = t; i < 16 * 1028; i += 512) (&accc[0][0])[i] = 0.f;
    __syncthreads();
    float bc = *bcp;
    f32x4 zero = {0.f, 0.f, 0.f, 0.f};

    for (int h = 0; h < HH; h++) {
        const unsigned short* qh = qb + ((size_t)(b * HH + h) << 16);  // *S*HD
        const unsigned short* kh = kb + ((size_t)(b * HH + h) << 16);
        const unsigned short* vh = vt + ((size_t)(b * HH + h) << 16);
        float wc = Wc[h];

        // Q A-frags: A[m=l15][k=quad*8+j], k-halves 0..31 / 32..63
        bf16x8 a0 = *(const bf16x8*)(qh + (q0 + l15) * 64 + quad * 8);
        bf16x8 a1 = *(const bf16x8*)(qh + (q0 + l15) * 64 + 32 + quad * 8);

        // S1: wave w owns cols [w*128, w*128+128)
        f32x4 sc[8];
#pragma unroll
        for (int nt = 0; nt < 8; nt++) {
            const unsigned short* kp = kh + (size_t)(w * 128 + nt * 16 + l15) * 64;
            bf16x8 b0 = *(const bf16x8*)(kp + quad * 8);
            bf16x8 b1 = *(const bf16x8*)(kp + 32 + quad * 8);
            f32x4 c = zero;
            c = __builtin_amdgcn_mfma_f32_16x16x32_bf16(a0, b0, c, 0, 0, 0);
            c = __builtin_amdgcn_mfma_f32_16x16x32_bf16(a1, b1, c, 0, 0, 0);
#pragma unroll
            for (int r = 0; r < 4; r++) sc[nt][r] = c[r] * 0.125f;   // 1/sqrt(64)
        }

        // per-row max: lane-local over 8 cols, then 16-lane group, then cross-wave via LDS
        float mx[4];
#pragma unroll
        for (int r = 0; r < 4; r++) {
            float m_ = sc[0][r];
#pragma unroll
            for (int nt = 1; nt < 8; nt++) m_ = fmaxf(m_, sc[nt][r]);
            m_ = fmaxf(m_, __shfl_xor(m_, 1));
            m_ = fmaxf(m_, __shfl_xor(m_, 2));
            m_ = fmaxf(m_, __shfl_xor(m_, 4));
            m_ = fmaxf(m_, __shfl_xor(m_, 8));
            mx[r] = m_;
        }
        if (l15 == 0) {
#pragma unroll
            for (int r = 0; r < 4; r++) red[w][quad * 4 + r] = mx[r];
        }
        __syncthreads();                       // B2
        float fm[4];
#pragma unroll
        for (int r = 0; r < 4; r++) {
            float m_ = red[0][quad * 4 + r];
#pragma unroll
            for (int ww = 1; ww < 8; ww++) m_ = fmaxf(m_, red[ww][quad * 4 + r]);
            fm[r] = m_;
        }
        __syncthreads();                       // B3 (red reuse)

        // exp + row sums
        float sm[4];
#pragma unroll
        for (int r = 0; r < 4; r++) {
            float s_ = 0.f;
#pragma unroll
            for (int nt = 0; nt < 8; nt++) {
                float p = __expf(sc[nt][r] - fm[r]);
                sc[nt][r] = p;
                s_ += p;
            }
            s_ += __shfl_xor(s_, 1);
            s_ += __shfl_xor(s_, 2);
            s_ += __shfl_xor(s_, 4);
            s_ += __shfl_xor(s_, 8);
            sm[r] = s_;
        }
        if (l15 == 0) {
#pragma unroll
            for (int r = 0; r < 4; r++) red[w][quad * 4 + r] = sm[r];
        }
        __syncthreads();                       // B4
        float inv[4];
#pragma unroll
        for (int r = 0; r < 4; r++) {
            float s_ = red[0][quad * 4 + r];
#pragma unroll
            for (int ww = 1; ww < 8; ww++) s_ += red[ww][quad * 4 + r];
            inv[r] = 1.f / s_;
        }

        // normalized P -> LDS (bf16) + attn_c accumulate (fp32)
#pragma unroll
        for (int nt = 0; nt < 8; nt++) {
            int col = w * 128 + nt * 16 + l15;
#pragma unroll
            for (int r = 0; r < 4; r++) {
                int row = quad * 4 + r;
                float pn = sc[nt][r] * inv[r];
                Ps[row][col] = f2bf(pn);
                accc[row][col] += wc * pn;
            }
        }
        __syncthreads();                       // B5: Ps complete

        // P.V: waves 0..3 hd-tiles x k[0,512); waves 4..7 same tiles x k[512,1024)
        int nt2 = w & 3, khalf = w >> 2;
        f32x4 o = zero;
#pragma unroll
        for (int ks = 0; ks < 512; ks += 32) {
            int kk = khalf * 512 + ks;
            bf16x8 ap = *(const bf16x8*)&Ps[l15][kk + quad * 8];
            bf16x8 bp = *(const bf16x8*)(vh + (size_t)(nt2 * 16 + l15) * SS + kk + quad * 8);
            o = __builtin_amdgcn_mfma_f32_16x16x32_bf16(ap, bp, o, 0, 0, 0);
        }
#pragma unroll
        for (int r = 0; r < 4; r++) Ob[khalf][quad * 4 + r][nt2 * 16 + l15] = o[r];
        __syncthreads();                       // B6

        // combine split-K halves, write x[b,s,h*64+d] (bf16)
        for (int i = t; i < 1024; i += 512) {
            int row = i >> 6, d = i & 63;
            float val = Ob[0][row][d] + Ob[1][row][d];
            xout[((size_t)(b * SS) + q0 + row) * DD + h * 64 + d] = f2bf(val);
        }
        __syncthreads();                       // B7: Ob/red/Ps safe for next head
    }

    // attn_c = acc + bc  -> [b,1,S,S]
    for (int i = t; i < 16 * 1024; i += 512) {
        int row = i >> 10, col = i & 1023;
        attc[((size_t)b * SS + q0 + row) * SS + col] = accc[row][col] + bc;
    }
}

extern "C" void kernel_launch(void* const* d_in, const int* in_sizes, int n_in,
                              void* d_out, int out_size, void* d_ws, size_t ws_size,
                              hipStream_t stream) {
    const float* query = (const float*)d_in[0];
    const float* key   = (const float*)d_in[1];
    const float* value = (const float*)d_in[2];
    const float* Wq = (const float*)d_in[3];
    const float* bq = (const float*)d_in[4];
    const float* Wk = (const float*)d_in[5];
    const float* bk = (const float*)d_in[6];
    const float* Wv = (const float*)d_in[7];
    const float* bv = (const float*)d_in[8];
    const float* Wo = (const float*)d_in[9];
    const float* bo = (const float*)d_in[10];
    const float* Wc = (const float*)d_in[11];
    const float* bc = (const float*)d_in[12];

    // workspace layout (64 MiB total)
    unsigned short* ws  = (unsigned short*)d_ws;
    unsigned short* xq  = ws;                       // 4M bf16: query
    unsigned short* xk  = xq  + (size_t)4194304;
    unsigned short* xv  = xk  + (size_t)4194304;
    unsigned short* wtq = xv  + (size_t)4194304;    // 1M bf16 each: W^T
    unsigned short* wtk = wtq + (size_t)1048576;
    unsigned short* wtv = wtk + (size_t)1048576;
    unsigned short* wto = wtv + (size_t)1048576;
    unsigned short* qb  = wto + (size_t)1048576;    // [b,h,s,hd]
    unsigned short* kb  = qb  + (size_t)4194304;    // [b,h,s,hd]
    unsigned short* vt  = kb  + (size_t)4194304;    // [b,h,hd,s]
    unsigned short* xat = vt  + (size_t)4194304;    // [b,s,d]

    float* out0 = (float*)d_out;                    // [B,S,D]
    float* attc = out0 + (size_t)4194304;           // [B,1,S,S]

    hipLaunchKernelGGL(cvt3, dim3(4096), dim3(256), 0, stream,
                       query, key, value, xq, xk, xv);
    hipLaunchKernelGGL(wtrans, dim3(32, 32, 4), dim3(256), 0, stream,
                       Wq, Wk, Wv, Wo, wtq, wtk, wtv, wto);
    hipLaunchKernelGGL(gemm_qkv, dim3(8, 32, 3), dim3(256), 0, stream,
                       xq, xk, xv, wtq, wtk, wtv, bq, bk, bv, qb, kb, vt);
    hipLaunchKernelGGL(attn_kernel, dim3(256), dim3(512), 0, stream,
                       qb, kb, vt, Wc, bc, xat, attc);
    hipLaunchKernelGGL(gemm_o, dim3(8, 32), dim3(256), 0, stream,
                       xat, wto, bo, out0);
}